// Round 10
// baseline (575.930 us; speedup 1.0000x reference)
//
#include <hip/hip_runtime.h>
#include <hip/hip_fp16.h>

#define BATCH   1024
#define IN      1024
#define OUT     40960
#define KF      7
#define BT      8            // batch rows per block: one 8-row fp16 table
#define THREADS 256
#define OTILE   1024         // outputs per block (4 consecutive per thread)

// Workspace:
//   pmeta : uint2 [OUT/256][KF][64][4]  {x = idx<<4 (LDS byte off), y = val bits}
//           wave-chunk-major: lane l holds outputs c256*256 + l*4 .. +3, so a
//           lane's 4 records for one k are 32 B contiguous (2 uint4 loads) and
//           a wave's k-slice is 2 KB contiguous.
//   xpk   : f16 [BATCH/8][IN][8]  x rounded fp16, 8 batch rows per 16-B granule
#define PMETA_BYTES ((size_t)OUT * KF * 8)                // 2,293,760
#define XPK_BYTES   ((size_t)(BATCH / 8) * IN * 8 * 2)    // 2,097,152

// Round-10: every structural probe except STORE WIDTH is exhausted (granule,
// meta volume, stage volume, store drain=4us, occupancy, ws persistence,
// channel spread: all neutral). All rounds used per-lane dword stores. If the
// L2 does not recognize a wave's 64x4B dword-store burst as full-line covered,
// it performs write-allocate READS -- a hidden ~168 MB fetch = ~26us, matching
// the unexplained residual. This version: each thread owns 4 CONSECUTIVE
// outputs -> one global_store_dwordx4 per (row): wave writes 1024 B/instr,
// unambiguously full-line; store instrs /4, meta loads /2 (uint4 pairs).
// Gather count and divergence statistics unchanged.

__global__ __launch_bounds__(THREADS)
void repack_kernel(const float* __restrict__ x, const float* __restrict__ vals,
                   const int* __restrict__ idx,
                   uint2* __restrict__ pmeta, __half* __restrict__ xpk)
{
    const int gid = blockIdx.x * THREADS + threadIdx.x;
    if (blockIdx.x < 512) {
        // ---- part A: x[1024][1024] f32 -> xpk[g][i][8] f16 ----
        const int g = gid >> 10;        // batch group 0..127
        const int i = gid & 1023;       // column
        const float* xb = x + (size_t)g * 8 * IN + i;
        union { __half h[8]; float4 f; } u;
#pragma unroll
        for (int r = 0; r < 8; ++r) u.h[r] = __float2half_rn(xb[(size_t)r * IN]);
        *(float4*)&xpk[(size_t)gid * 8] = u.f;   // coalesced 16-B store
    } else {
        // ---- part B: idx/vals [OUT][KF] -> pmeta[c256][k][l][j] ----
        // linear dst t2 = (c256*KF + k)*256 + l4, where o = c256*256 + l4
        const int t2   = gid - 512 * THREADS;    // 0 .. 286719
        const int c256 = t2 / (KF * 256);
        const int rem  = t2 % (KF * 256);
        const int k    = rem >> 8;
        const int l4   = rem & 255;
        const int o    = c256 * 256 + l4;
        const size_t src = (size_t)o * KF + k;
        uint2 m;
        m.x = (unsigned)(idx[src] << 4);         // byte offset into xs table
        m.y = __float_as_uint(vals[src]);
        pmeta[t2] = m;
    }
}

__global__ __launch_bounds__(THREADS, 5)
void sparse_proj(const uint2* __restrict__ pmeta, const __half* __restrict__ xpk,
                 float* __restrict__ y)
{
    // one 8-row table: xs[i*16B] = rows b0 .. b0+7 (fp16)
    __shared__ __align__(16) __half xs[IN * 8];   // 16 KB

    const int t  = threadIdx.x;
    const int b0 = blockIdx.y * BT;

    // ---- stage: straight 16 KB copy, already fp16 + gather-layout ----
    {
        const float4* src = (const float4*)(xpk + (size_t)blockIdx.y * IN * 8);
        float4* dst = (float4*)xs;
#pragma unroll
        for (int r = 0; r < 4; ++r) dst[t + r * THREADS] = src[t + r * THREADS];
    }
    __syncthreads();

    const int w    = t >> 6;
    const int lane = t & 63;
    const int c256 = blockIdx.x * 4 + w;   // this wave's 256-output chunk

    // per-k record base, in uint4 units: (c256*KF + k)*128 + lane*2
    const uint4* mb4 = (const uint4*)pmeta + (size_t)c256 * KF * 128 + lane * 2;

    float acc[4][BT];
#pragma unroll
    for (int j = 0; j < 4; ++j)
#pragma unroll
        for (int r = 0; r < BT; ++r) acc[j][r] = 0.0f;

    // double-buffered meta (all indices static after unroll)
    uint4 q0 = mb4[0], q1 = mb4[1];
#pragma unroll
    for (int k = 0; k < KF; ++k) {
        uint4 n0, n1;
        if (k + 1 < KF) { n0 = mb4[(k + 1) * 128]; n1 = mb4[(k + 1) * 128 + 1]; }

        const unsigned off0 = q0.x, off1 = q0.z, off2 = q1.x, off3 = q1.z;
        const float v0 = __uint_as_float(q0.y);
        const float v1 = __uint_as_float(q0.w);
        const float v2 = __uint_as_float(q1.y);
        const float v3 = __uint_as_float(q1.w);

#pragma unroll
        for (int j = 0; j < 4; ++j) {
            const unsigned off = (j == 0) ? off0 : (j == 1) ? off1
                               : (j == 2) ? off2 : off3;
            const float v = (j == 0) ? v0 : (j == 1) ? v1 : (j == 2) ? v2 : v3;
            const float4 g = *(const float4*)((const char*)xs + off); // 8 rows
            const __half2 a0 = *(const __half2*)&g.x;
            const __half2 a1 = *(const __half2*)&g.y;
            const __half2 a2 = *(const __half2*)&g.z;
            const __half2 a3 = *(const __half2*)&g.w;
            acc[j][0] = fmaf(v, __low2float(a0),  acc[j][0]);
            acc[j][1] = fmaf(v, __high2float(a0), acc[j][1]);
            acc[j][2] = fmaf(v, __low2float(a1),  acc[j][2]);
            acc[j][3] = fmaf(v, __high2float(a1), acc[j][3]);
            acc[j][4] = fmaf(v, __low2float(a2),  acc[j][4]);
            acc[j][5] = fmaf(v, __high2float(a2), acc[j][5]);
            acc[j][6] = fmaf(v, __low2float(a3),  acc[j][6]);
            acc[j][7] = fmaf(v, __high2float(a3), acc[j][7]);
        }
        q0 = n0; q1 = n1;
    }

    // ---- store: one dwordx4 per row -> wave writes 1024 B contiguous,
    // full-line covered (no write-allocate ambiguity). ----
    const int o0 = blockIdx.x * OTILE + w * 256 + lane * 4;
#pragma unroll
    for (int r = 0; r < BT; ++r) {
        float4 f;
        f.x = acc[0][r]; f.y = acc[1][r]; f.z = acc[2][r]; f.w = acc[3][r];
        *(float4*)&y[(size_t)(b0 + r) * OUT + o0] = f;
    }
}

extern "C" void kernel_launch(void* const* d_in, const int* in_sizes, int n_in,
                              void* d_out, int out_size, void* d_ws, size_t ws_size,
                              hipStream_t stream) {
    const float* x    = (const float*)d_in[0];   // [1024, 1024] fp32
    const float* vals = (const float*)d_in[1];   // [40960, 7]  fp32
    const int*   idx  = (const int*)d_in[2];     // [40960, 7]  int32
    float*       y    = (float*)d_out;           // [1024, 40960] fp32

    uint2*  pmeta = (uint2*)d_ws;
    __half* xpk   = (__half*)((char*)d_ws + PMETA_BYTES);

    // 512 blocks for xpk (131072 threads) + 1120 blocks for pmeta (286720)
    repack_kernel<<<dim3(512 + 1120), dim3(THREADS), 0, stream>>>(
        x, vals, idx, pmeta, xpk);

    dim3 grid(OUT / OTILE, BATCH / BT);          // (40, 128) = 5120 blocks
    sparse_proj<<<grid, dim3(THREADS), 0, stream>>>(pmeta, xpk, y);
}